// Round 2
// 369.544 us; speedup vs baseline: 1.0151x; 1.0151x over previous
//
#include <hip/hip_runtime.h>
#include <hip/hip_bf16.h>
#include <cmath>

// Problem constants (fixed by setup_inputs)
constexpr int S = 128;   // num_states
constexpr int C = 32;    // num_chains
constexpr int N = 4096;  // num_nodes
constexpr int T = 512;   // num_iters

// Output layout (flat float32, concatenated in reference return order)
constexpr size_t OFF1 = 0;                          // log_observed_state_probs  [T,N]
constexpr size_t OFF2 = OFF1 + (size_t)T * N;       // log_observed_state_probs_ [T,C,N]
constexpr size_t OFF3 = OFF2 + (size_t)T * C * N;   // log_hidden_state_probs   [T,C,S]
constexpr size_t OFF4 = OFF3 + (size_t)T * C * S;   // log_emission             [S,N]
constexpr size_t OFF5 = OFF4 + (size_t)S * N;       // log_chain_weights        [T,C]

typedef __bf16 bf16x8 __attribute__((ext_vector_type(8)));
typedef float floatx4 __attribute__((ext_vector_type(4)));
typedef float floatx16 __attribute__((ext_vector_type(16)));

__device__ __forceinline__ void split_bf16(float p, __bf16& hi, __bf16& lo) {
    hi = (__bf16)p;
    lo = (__bf16)(p - (float)hi);
}

// ---------------------------------------------------------------------------
// Fused softmax kernel, one launch, 352 blocks x 256 threads (unchanged).
// ---------------------------------------------------------------------------
__global__ __launch_bounds__(256) void fused_softmax_kernel(
        const float* __restrict__ emis, const float* __restrict__ cw,
        const float* __restrict__ trans, const float* __restrict__ init,
        float* __restrict__ out3, float* __restrict__ out4, float* __restrict__ out5,
        __bf16* __restrict__ pET, float* __restrict__ pcw,
        __bf16* __restrict__ Rhi, __bf16* __restrict__ Rlo,
        __bf16* __restrict__ Thi, __bf16* __restrict__ Tlo,
        __bf16* __restrict__ Hhi, __bf16* __restrict__ Hlo) {
    const int b = blockIdx.x;
    const int tid = threadIdx.x;

    if (b >= 288) {   // ---- chain weights: 8 rows of 32 per block ----
        const int row = (b - 288) * 8 + (tid >> 5);
        const int j = tid & 31;
        const float v = cw[(size_t)row * C + j];
        float m = v;
#pragma unroll
        for (int o = 16; o > 0; o >>= 1) m = fmaxf(m, __shfl_xor(m, o, 64));
        float s = __expf(v - m);
#pragma unroll
        for (int o = 16; o > 0; o >>= 1) s += __shfl_xor(s, o, 64);
        const float lv = v - m - __logf(s);
        out5[(size_t)row * C + j] = lv;
        pcw[(size_t)row * C + j] = __expf(lv);
        return;
    }

    const float* x;
    int cols, row;
    if (b < 128)      { row = b;       cols = N; x = emis  + (size_t)row * N; }
    else if (b < 256) { row = b - 128; cols = S; x = trans + (size_t)row * S; }
    else              { row = b - 256; cols = S; x = init  + (size_t)row * S; }

    __shared__ float sm[4];
    __shared__ float ss[4];

    float m = -INFINITY;
    for (int j = tid; j < cols; j += 256) m = fmaxf(m, x[j]);
#pragma unroll
    for (int o = 32; o > 0; o >>= 1) m = fmaxf(m, __shfl_xor(m, o, 64));
    const int wid = tid >> 6;
    if ((tid & 63) == 0) sm[wid] = m;
    __syncthreads();
    m = fmaxf(fmaxf(sm[0], sm[1]), fmaxf(sm[2], sm[3]));

    float s = 0.f;
    for (int j = tid; j < cols; j += 256) s += __expf(x[j] - m);
#pragma unroll
    for (int o = 32; o > 0; o >>= 1) s += __shfl_xor(s, o, 64);
    if ((tid & 63) == 0) ss[wid] = s;
    __syncthreads();
    s = ss[0] + ss[1] + ss[2] + ss[3];
    const float lse = m + __logf(s);

    for (int j = tid; j < cols; j += 256) {
        const float v = x[j] - lse;
        const float p = __expf(v);
        if (b < 128) {
            out4[(size_t)row * N + j] = v;
            pET[(size_t)j * S + row] = (__bf16)p;
        } else if (b < 256) {
            __bf16 hi, lo; split_bf16(p, hi, lo);
            Rhi[(size_t)row * S + j] = hi; Rlo[(size_t)row * S + j] = lo;
            Thi[(size_t)j * S + row] = hi; Tlo[(size_t)j * S + row] = lo;
        } else {
            out3[((size_t)0 * C + row) * S + j] = v;
            __bf16 hi, lo; split_bf16(p, hi, lo);
            Hhi[(size_t)row * S + j] = hi; Hlo[(size_t)row * S + j] = lo;
        }
    }
}

// ---------------------------------------------------------------------------
// One H-doubling round (m = 2^(r-1)), hi/lo bf16 pair MFMA. [R3-proven:
// ~42 us for all 9 launches; cooperative grid.sync variant measured 300 us.]
// ---------------------------------------------------------------------------
__global__ __launch_bounds__(256) void h_round_kernel(
        const __bf16* __restrict__ Rhi, const __bf16* __restrict__ Rlo,
        const __bf16* __restrict__ Thi, const __bf16* __restrict__ Tlo,
        __bf16* __restrict__ Rnhi, __bf16* __restrict__ Rnlo,
        __bf16* __restrict__ Tnhi, __bf16* __restrict__ Tnlo,
        __bf16* __restrict__ Hhi, __bf16* __restrict__ Hlo,
        float* __restrict__ out3, int m, int count) {
    const int b = blockIdx.x;
    const int w = threadIdx.x >> 6;
    const int lane = threadIdx.x & 63;
    const int lr = lane & 15;
    const int quad = lane >> 4;

    if (b < count) {
        const __bf16* Ahi = Hhi + (size_t)b * C * S;
        const __bf16* Alo = Hlo + (size_t)b * C * S;
        floatx4 acc[2][2];
#pragma unroll
        for (int mt = 0; mt < 2; mt++)
#pragma unroll
            for (int nt = 0; nt < 2; nt++) acc[mt][nt] = (floatx4)0.f;

#pragma unroll
        for (int kt = 0; kt < 4; kt++) {
            const int ko = kt * 32 + quad * 8;
            const bf16x8 ah0 = *reinterpret_cast<const bf16x8*>(&Ahi[(size_t)lr * S + ko]);
            const bf16x8 ah1 = *reinterpret_cast<const bf16x8*>(&Ahi[(size_t)(16 + lr) * S + ko]);
            const bf16x8 al0 = *reinterpret_cast<const bf16x8*>(&Alo[(size_t)lr * S + ko]);
            const bf16x8 al1 = *reinterpret_cast<const bf16x8*>(&Alo[(size_t)(16 + lr) * S + ko]);
            const bf16x8 bh0 = *reinterpret_cast<const bf16x8*>(&Thi[(size_t)(w * 32 + lr) * S + ko]);
            const bf16x8 bh1 = *reinterpret_cast<const bf16x8*>(&Thi[(size_t)(w * 32 + 16 + lr) * S + ko]);
            const bf16x8 bl0 = *reinterpret_cast<const bf16x8*>(&Tlo[(size_t)(w * 32 + lr) * S + ko]);
            const bf16x8 bl1 = *reinterpret_cast<const bf16x8*>(&Tlo[(size_t)(w * 32 + 16 + lr) * S + ko]);
            acc[0][0] = __builtin_amdgcn_mfma_f32_16x16x32_bf16(ah0, bh0, acc[0][0], 0, 0, 0);
            acc[0][0] = __builtin_amdgcn_mfma_f32_16x16x32_bf16(ah0, bl0, acc[0][0], 0, 0, 0);
            acc[0][0] = __builtin_amdgcn_mfma_f32_16x16x32_bf16(al0, bh0, acc[0][0], 0, 0, 0);
            acc[0][1] = __builtin_amdgcn_mfma_f32_16x16x32_bf16(ah0, bh1, acc[0][1], 0, 0, 0);
            acc[0][1] = __builtin_amdgcn_mfma_f32_16x16x32_bf16(ah0, bl1, acc[0][1], 0, 0, 0);
            acc[0][1] = __builtin_amdgcn_mfma_f32_16x16x32_bf16(al0, bh1, acc[0][1], 0, 0, 0);
            acc[1][0] = __builtin_amdgcn_mfma_f32_16x16x32_bf16(ah1, bh0, acc[1][0], 0, 0, 0);
            acc[1][0] = __builtin_amdgcn_mfma_f32_16x16x32_bf16(ah1, bl0, acc[1][0], 0, 0, 0);
            acc[1][0] = __builtin_amdgcn_mfma_f32_16x16x32_bf16(al1, bh0, acc[1][0], 0, 0, 0);
            acc[1][1] = __builtin_amdgcn_mfma_f32_16x16x32_bf16(ah1, bh1, acc[1][1], 0, 0, 0);
            acc[1][1] = __builtin_amdgcn_mfma_f32_16x16x32_bf16(ah1, bl1, acc[1][1], 0, 0, 0);
            acc[1][1] = __builtin_amdgcn_mfma_f32_16x16x32_bf16(al1, bh1, acc[1][1], 0, 0, 0);
        }

        const size_t t = (size_t)m + b;
#pragma unroll
        for (int mt = 0; mt < 2; mt++) {
#pragma unroll
            for (int nt = 0; nt < 2; nt++) {
#pragma unroll
                for (int reg = 0; reg < 4; reg++) {
                    const int c = mt * 16 + quad * 4 + reg;
                    const int n = w * 32 + nt * 16 + lr;
                    const float p = acc[mt][nt][reg];
                    __bf16 hi, lo; split_bf16(p, hi, lo);
                    Hhi[(t * C + c) * S + n] = hi;
                    Hlo[(t * C + c) * S + n] = lo;
                    out3[(t * C + c) * S + n] = __logf(p);
                }
            }
        }
    } else {
        const int rb = b - count;
        floatx4 acc[2];
        acc[0] = (floatx4)0.f; acc[1] = (floatx4)0.f;
#pragma unroll
        for (int kt = 0; kt < 4; kt++) {
            const int ko = kt * 32 + quad * 8;
            const bf16x8 ah = *reinterpret_cast<const bf16x8*>(&Rhi[(size_t)(rb * 16 + lr) * S + ko]);
            const bf16x8 al = *reinterpret_cast<const bf16x8*>(&Rlo[(size_t)(rb * 16 + lr) * S + ko]);
            const bf16x8 bh0 = *reinterpret_cast<const bf16x8*>(&Thi[(size_t)(w * 32 + lr) * S + ko]);
            const bf16x8 bh1 = *reinterpret_cast<const bf16x8*>(&Thi[(size_t)(w * 32 + 16 + lr) * S + ko]);
            const bf16x8 bl0 = *reinterpret_cast<const bf16x8*>(&Tlo[(size_t)(w * 32 + lr) * S + ko]);
            const bf16x8 bl1 = *reinterpret_cast<const bf16x8*>(&Tlo[(size_t)(w * 32 + 16 + lr) * S + ko]);
            acc[0] = __builtin_amdgcn_mfma_f32_16x16x32_bf16(ah, bh0, acc[0], 0, 0, 0);
            acc[0] = __builtin_amdgcn_mfma_f32_16x16x32_bf16(ah, bl0, acc[0], 0, 0, 0);
            acc[0] = __builtin_amdgcn_mfma_f32_16x16x32_bf16(al, bh0, acc[0], 0, 0, 0);
            acc[1] = __builtin_amdgcn_mfma_f32_16x16x32_bf16(ah, bh1, acc[1], 0, 0, 0);
            acc[1] = __builtin_amdgcn_mfma_f32_16x16x32_bf16(ah, bl1, acc[1], 0, 0, 0);
            acc[1] = __builtin_amdgcn_mfma_f32_16x16x32_bf16(al, bh1, acc[1], 0, 0, 0);
        }
#pragma unroll
        for (int nt = 0; nt < 2; nt++) {
#pragma unroll
            for (int reg = 0; reg < 4; reg++) {
                const int row = rb * 16 + quad * 4 + reg;
                const int col = w * 32 + nt * 16 + lr;
                const float p = acc[nt][reg];
                __bf16 hi, lo; split_bf16(p, hi, lo);
                Rnhi[(size_t)row * S + col] = hi; Rnlo[(size_t)row * S + col] = lo;
                Tnhi[(size_t)col * S + row] = hi; Tnlo[(size_t)col * S + row] = lo;
            }
        }
    }
}

// ---------------------------------------------------------------------------
// Observation GEMM v4: wave owns (1 t x 128 n) instead of (2 t x 64 n).
// Same block shape (512 thr = 8 waves <-> 8 t's), same LDS-staged pET tile
// (kept: amortizes 32-line B gathers into coalesced loads), same 32 MFMA /
// wave and ~same VGPR (acc = 4 x floatx16). Delta vs v3:
//   - out2 epilogue emits 512 B contiguous per (t,c) row (4 back-to-back
//     128 B store instrs) instead of 256 B -> halves DRAM row activations
//     for the 268 MB out2 stream (theory: obs is write-locality-bound,
//     ~2-3 TB/s effective vs fill's 6.3 TB/s sequential).
//   - out1 stores become one 512 B burst per (t, n-block).
//   - A-operand global gathers per wave halve (8 instead of 16).
//   out2[t,c,n] = log(O[c,n]);  out1[t,n] = log(sum_c pcw[t,c]*O[c,n])
// ---------------------------------------------------------------------------
__global__ __launch_bounds__(512, 4) void obs_mfma_kernel(
        const __bf16* __restrict__ Hb,    // [T,C,S] (hi plane)
        const __bf16* __restrict__ pET,   // [N,S]
        const float* __restrict__ pcw,    // [T,C]
        float* __restrict__ out1,
        float* __restrict__ out2) {
    constexpr int BPITCH = 264;  // bytes per LDS row (256 data + 8 pad)
    __shared__ __align__(16) unsigned char Bs[128 * BPITCH];  // 33 KB
    __shared__ float sw[8][C];

    const int tid = threadIdx.x;
    const int w = tid >> 6;
    const int lane = tid & 63;
    const int l31 = lane & 31;
    const int half = lane >> 5;
    const int nblk = blockIdx.x * 128;
    const int tbase = blockIdx.y * 8;
    const int t = tbase + w;           // wave owns one t, full 128-n width

    // Stage pET rows [nblk, nblk+128) into LDS (padded pitch, coalesced 16B).
#pragma unroll
    for (int p = 0; p < 4; p++) {
        const int idx = p * 512 + tid;     // 0..2047
        const int row = idx >> 4;          // 0..127
        const int c16 = idx & 15;          // 16B chunk within row
        const float4 v = *reinterpret_cast<const float4*>(
            pET + (size_t)(nblk + row) * S + c16 * 8);
        *reinterpret_cast<float4*>(Bs + row * BPITCH + c16 * 16) = v;
    }
    if (tid < 256) sw[tid >> 5][tid & 31] =
        pcw[(size_t)(tbase + (tid >> 5)) * C + (tid & 31)];
    __syncthreads();

    const __bf16* A = Hb + (size_t)t * C * S;

    floatx16 acc[4];   // [ntile], 128 n-cols for one t
#pragma unroll
    for (int nt = 0; nt < 4; nt++) acc[nt] = (floatx16)0.f;

#pragma unroll
    for (int ks = 0; ks < 8; ks++) {
        const int ko = ks * 16 + half * 8;
        const bf16x8 a  = *reinterpret_cast<const bf16x8*>(&A[(size_t)l31 * S + ko]);
        const bf16x8 b0 = *reinterpret_cast<const bf16x8*>(Bs + (l31) * BPITCH + ko * 2);
        const bf16x8 b1 = *reinterpret_cast<const bf16x8*>(Bs + (32 + l31) * BPITCH + ko * 2);
        const bf16x8 b2 = *reinterpret_cast<const bf16x8*>(Bs + (64 + l31) * BPITCH + ko * 2);
        const bf16x8 b3 = *reinterpret_cast<const bf16x8*>(Bs + (96 + l31) * BPITCH + ko * 2);
        acc[0] = __builtin_amdgcn_mfma_f32_32x32x16_bf16(a, b0, acc[0], 0, 0, 0);
        acc[1] = __builtin_amdgcn_mfma_f32_32x32x16_bf16(a, b1, acc[1], 0, 0, 0);
        acc[2] = __builtin_amdgcn_mfma_f32_32x32x16_bf16(a, b2, acc[2], 0, 0, 0);
        acc[3] = __builtin_amdgcn_mfma_f32_32x32x16_bf16(a, b3, acc[3], 0, 0, 0);
    }

    // Epilogue: per output row (t,c), write 4 consecutive 128 B chunks
    // (512 B contiguous burst); accumulate out1 partials per n-lane.
    float p0 = 0.f, p1 = 0.f, p2 = 0.f, p3 = 0.f;
#pragma unroll
    for (int reg = 0; reg < 16; reg++) {
        const int c = (reg & 3) + 8 * (reg >> 2) + 4 * half;
        const float wv = sw[w][c];
        const float o0 = acc[0][reg];
        const float o1 = acc[1][reg];
        const float o2 = acc[2][reg];
        const float o3 = acc[3][reg];
        float* rowp = &out2[((size_t)t * C + c) * N + nblk + l31];
        __builtin_nontemporal_store(__logf(o0), rowp);
        __builtin_nontemporal_store(__logf(o1), rowp + 32);
        __builtin_nontemporal_store(__logf(o2), rowp + 64);
        __builtin_nontemporal_store(__logf(o3), rowp + 96);
        p0 = fmaf(wv, o0, p0);
        p1 = fmaf(wv, o1, p1);
        p2 = fmaf(wv, o2, p2);
        p3 = fmaf(wv, o3, p3);
    }
    p0 += __shfl_xor(p0, 32, 64);
    p1 += __shfl_xor(p1, 32, 64);
    p2 += __shfl_xor(p2, 32, 64);
    p3 += __shfl_xor(p3, 32, 64);
    if (half == 0) {
        float* o1p = &out1[(size_t)t * N + nblk + l31];
        __builtin_nontemporal_store(__logf(p0), o1p);
        __builtin_nontemporal_store(__logf(p1), o1p + 32);
        __builtin_nontemporal_store(__logf(p2), o1p + 64);
        __builtin_nontemporal_store(__logf(p3), o1p + 96);
    }
}

// ---------------------------------------------------------------------------
extern "C" void kernel_launch(void* const* d_in, const int* in_sizes, int n_in,
                              void* d_out, int out_size, void* d_ws, size_t ws_size,
                              hipStream_t stream) {
    const float* in_init  = (const float*)d_in[0];  // [C,S]
    const float* in_cw    = (const float*)d_in[1];  // [T,C]
    const float* in_emis  = (const float*)d_in[2];  // [S,N]
    const float* in_trans = (const float*)d_in[3];  // [S,S]

    float* out = (float*)d_out;

    // Workspace layout (~9.5 MB, 256B aligned)
    char* wsb = (char*)d_ws;
    float*  ws_pcw = (float*)(wsb);                                  // 64 KB [T,C]
    __bf16* ws_pET = (__bf16*)(wsb + (64u << 10));                   // 1 MB  [N,S]
    __bf16* ws_Hhi = (__bf16*)(wsb + (1088u << 10));                 // 4 MB  [T,C,S]
    __bf16* ws_Hlo = (__bf16*)(wsb + (5184u << 10));                 // 4 MB  [T,C,S]
    __bf16* Pslot[2][4];
    for (int sl = 0; sl < 2; sl++)
        for (int pl = 0; pl < 4; pl++)
            Pslot[sl][pl] = (__bf16*)(wsb + (9280u << 10) + (size_t)(sl * 4 + pl) * (32u << 10));

    // 1) All softmaxes in one launch.
    fused_softmax_kernel<<<352, 256, 0, stream>>>(
        in_emis, in_cw, in_trans, in_init,
        out + OFF3, out + OFF4, out + OFF5,
        ws_pET, ws_pcw,
        Pslot[0][0], Pslot[0][1], Pslot[0][2], Pslot[0][3],
        ws_Hhi, ws_Hlo);

    // 2) H-doubling rounds (hi/lo-pair MFMA), 9 separate launches (proven
    //    ~42 us total; cooperative-sync variant was 300 us).
    for (int r = 1; r <= 9; r++) {
        const int m = 1 << (r - 1);
        const int count = (m < T - m) ? m : (T - m);
        const int s = (r - 1) & 1, d = r & 1;
        const int extra = (r < 9) ? 8 : 0;
        h_round_kernel<<<count + extra, 256, 0, stream>>>(
            Pslot[s][0], Pslot[s][1], Pslot[s][2], Pslot[s][3],
            Pslot[d][0], Pslot[d][1], Pslot[d][2], Pslot[d][3],
            ws_Hhi, ws_Hlo, out + OFF3, m, count);
    }

    // 3) Observation GEMM v4: 1-t-per-wave, 512 B row-bursts.
    obs_mfma_kernel<<<dim3(N / 128, T / 8), 512, 0, stream>>>(
        ws_Hhi, ws_pET, ws_pcw, out + OFF1, out + OFF2);
}

// Round 3
// 363.789 us; speedup vs baseline: 1.0311x; 1.0158x over previous
//
#include <hip/hip_runtime.h>
#include <hip/hip_bf16.h>
#include <cmath>

// Problem constants (fixed by setup_inputs)
constexpr int S = 128;   // num_states
constexpr int C = 32;    // num_chains
constexpr int N = 4096;  // num_nodes
constexpr int T = 512;   // num_iters

// Output layout (flat float32, concatenated in reference return order)
constexpr size_t OFF1 = 0;                          // log_observed_state_probs  [T,N]
constexpr size_t OFF2 = OFF1 + (size_t)T * N;       // log_observed_state_probs_ [T,C,N]
constexpr size_t OFF3 = OFF2 + (size_t)T * C * N;   // log_hidden_state_probs   [T,C,S]
constexpr size_t OFF4 = OFF3 + (size_t)T * C * S;   // log_emission             [S,N]
constexpr size_t OFF5 = OFF4 + (size_t)S * N;       // log_chain_weights        [T,C]

typedef __bf16 bf16x8 __attribute__((ext_vector_type(8)));
typedef float floatx4 __attribute__((ext_vector_type(4)));
typedef float floatx16 __attribute__((ext_vector_type(16)));

__device__ __forceinline__ void split_bf16(float p, __bf16& hi, __bf16& lo) {
    hi = (__bf16)p;
    lo = (__bf16)(p - (float)hi);
}

// ---------------------------------------------------------------------------
// Fused softmax kernel, one launch, 352 blocks x 256 threads (unchanged).
// ---------------------------------------------------------------------------
__global__ __launch_bounds__(256) void fused_softmax_kernel(
        const float* __restrict__ emis, const float* __restrict__ cw,
        const float* __restrict__ trans, const float* __restrict__ init,
        float* __restrict__ out3, float* __restrict__ out4, float* __restrict__ out5,
        __bf16* __restrict__ pET, float* __restrict__ pcw,
        __bf16* __restrict__ Rhi, __bf16* __restrict__ Rlo,
        __bf16* __restrict__ Thi, __bf16* __restrict__ Tlo,
        __bf16* __restrict__ Hhi, __bf16* __restrict__ Hlo) {
    const int b = blockIdx.x;
    const int tid = threadIdx.x;

    if (b >= 288) {   // ---- chain weights: 8 rows of 32 per block ----
        const int row = (b - 288) * 8 + (tid >> 5);
        const int j = tid & 31;
        const float v = cw[(size_t)row * C + j];
        float m = v;
#pragma unroll
        for (int o = 16; o > 0; o >>= 1) m = fmaxf(m, __shfl_xor(m, o, 64));
        float s = __expf(v - m);
#pragma unroll
        for (int o = 16; o > 0; o >>= 1) s += __shfl_xor(s, o, 64);
        const float lv = v - m - __logf(s);
        out5[(size_t)row * C + j] = lv;
        pcw[(size_t)row * C + j] = __expf(lv);
        return;
    }

    const float* x;
    int cols, row;
    if (b < 128)      { row = b;       cols = N; x = emis  + (size_t)row * N; }
    else if (b < 256) { row = b - 128; cols = S; x = trans + (size_t)row * S; }
    else              { row = b - 256; cols = S; x = init  + (size_t)row * S; }

    __shared__ float sm[4];
    __shared__ float ss[4];

    float m = -INFINITY;
    for (int j = tid; j < cols; j += 256) m = fmaxf(m, x[j]);
#pragma unroll
    for (int o = 32; o > 0; o >>= 1) m = fmaxf(m, __shfl_xor(m, o, 64));
    const int wid = tid >> 6;
    if ((tid & 63) == 0) sm[wid] = m;
    __syncthreads();
    m = fmaxf(fmaxf(sm[0], sm[1]), fmaxf(sm[2], sm[3]));

    float s = 0.f;
    for (int j = tid; j < cols; j += 256) s += __expf(x[j] - m);
#pragma unroll
    for (int o = 32; o > 0; o >>= 1) s += __shfl_xor(s, o, 64);
    if ((tid & 63) == 0) ss[wid] = s;
    __syncthreads();
    s = ss[0] + ss[1] + ss[2] + ss[3];
    const float lse = m + __logf(s);

    for (int j = tid; j < cols; j += 256) {
        const float v = x[j] - lse;
        const float p = __expf(v);
        if (b < 128) {
            out4[(size_t)row * N + j] = v;
            pET[(size_t)j * S + row] = (__bf16)p;
        } else if (b < 256) {
            __bf16 hi, lo; split_bf16(p, hi, lo);
            Rhi[(size_t)row * S + j] = hi; Rlo[(size_t)row * S + j] = lo;
            Thi[(size_t)j * S + row] = hi; Tlo[(size_t)j * S + row] = lo;
        } else {
            out3[((size_t)0 * C + row) * S + j] = v;
            __bf16 hi, lo; split_bf16(p, hi, lo);
            Hhi[(size_t)row * S + j] = hi; Hlo[(size_t)row * S + j] = lo;
        }
    }
}

// ---------------------------------------------------------------------------
// One H-doubling round (m = 2^(r-1)), hi/lo bf16 pair MFMA. [R3-proven:
// ~42 us for all 9 launches; cooperative grid.sync variant measured 300 us.]
// ---------------------------------------------------------------------------
__global__ __launch_bounds__(256) void h_round_kernel(
        const __bf16* __restrict__ Rhi, const __bf16* __restrict__ Rlo,
        const __bf16* __restrict__ Thi, const __bf16* __restrict__ Tlo,
        __bf16* __restrict__ Rnhi, __bf16* __restrict__ Rnlo,
        __bf16* __restrict__ Tnhi, __bf16* __restrict__ Tnlo,
        __bf16* __restrict__ Hhi, __bf16* __restrict__ Hlo,
        float* __restrict__ out3, int m, int count) {
    const int b = blockIdx.x;
    const int w = threadIdx.x >> 6;
    const int lane = threadIdx.x & 63;
    const int lr = lane & 15;
    const int quad = lane >> 4;

    if (b < count) {
        const __bf16* Ahi = Hhi + (size_t)b * C * S;
        const __bf16* Alo = Hlo + (size_t)b * C * S;
        floatx4 acc[2][2];
#pragma unroll
        for (int mt = 0; mt < 2; mt++)
#pragma unroll
            for (int nt = 0; nt < 2; nt++) acc[mt][nt] = (floatx4)0.f;

#pragma unroll
        for (int kt = 0; kt < 4; kt++) {
            const int ko = kt * 32 + quad * 8;
            const bf16x8 ah0 = *reinterpret_cast<const bf16x8*>(&Ahi[(size_t)lr * S + ko]);
            const bf16x8 ah1 = *reinterpret_cast<const bf16x8*>(&Ahi[(size_t)(16 + lr) * S + ko]);
            const bf16x8 al0 = *reinterpret_cast<const bf16x8*>(&Alo[(size_t)lr * S + ko]);
            const bf16x8 al1 = *reinterpret_cast<const bf16x8*>(&Alo[(size_t)(16 + lr) * S + ko]);
            const bf16x8 bh0 = *reinterpret_cast<const bf16x8*>(&Thi[(size_t)(w * 32 + lr) * S + ko]);
            const bf16x8 bh1 = *reinterpret_cast<const bf16x8*>(&Thi[(size_t)(w * 32 + 16 + lr) * S + ko]);
            const bf16x8 bl0 = *reinterpret_cast<const bf16x8*>(&Tlo[(size_t)(w * 32 + lr) * S + ko]);
            const bf16x8 bl1 = *reinterpret_cast<const bf16x8*>(&Tlo[(size_t)(w * 32 + 16 + lr) * S + ko]);
            acc[0][0] = __builtin_amdgcn_mfma_f32_16x16x32_bf16(ah0, bh0, acc[0][0], 0, 0, 0);
            acc[0][0] = __builtin_amdgcn_mfma_f32_16x16x32_bf16(ah0, bl0, acc[0][0], 0, 0, 0);
            acc[0][0] = __builtin_amdgcn_mfma_f32_16x16x32_bf16(al0, bh0, acc[0][0], 0, 0, 0);
            acc[0][1] = __builtin_amdgcn_mfma_f32_16x16x32_bf16(ah0, bh1, acc[0][1], 0, 0, 0);
            acc[0][1] = __builtin_amdgcn_mfma_f32_16x16x32_bf16(ah0, bl1, acc[0][1], 0, 0, 0);
            acc[0][1] = __builtin_amdgcn_mfma_f32_16x16x32_bf16(al0, bh1, acc[0][1], 0, 0, 0);
            acc[1][0] = __builtin_amdgcn_mfma_f32_16x16x32_bf16(ah1, bh0, acc[1][0], 0, 0, 0);
            acc[1][0] = __builtin_amdgcn_mfma_f32_16x16x32_bf16(ah1, bl0, acc[1][0], 0, 0, 0);
            acc[1][0] = __builtin_amdgcn_mfma_f32_16x16x32_bf16(al1, bh0, acc[1][0], 0, 0, 0);
            acc[1][1] = __builtin_amdgcn_mfma_f32_16x16x32_bf16(ah1, bh1, acc[1][1], 0, 0, 0);
            acc[1][1] = __builtin_amdgcn_mfma_f32_16x16x32_bf16(ah1, bl1, acc[1][1], 0, 0, 0);
            acc[1][1] = __builtin_amdgcn_mfma_f32_16x16x32_bf16(al1, bh1, acc[1][1], 0, 0, 0);
        }

        const size_t t = (size_t)m + b;
#pragma unroll
        for (int mt = 0; mt < 2; mt++) {
#pragma unroll
            for (int nt = 0; nt < 2; nt++) {
#pragma unroll
                for (int reg = 0; reg < 4; reg++) {
                    const int c = mt * 16 + quad * 4 + reg;
                    const int n = w * 32 + nt * 16 + lr;
                    const float p = acc[mt][nt][reg];
                    __bf16 hi, lo; split_bf16(p, hi, lo);
                    Hhi[(t * C + c) * S + n] = hi;
                    Hlo[(t * C + c) * S + n] = lo;
                    out3[(t * C + c) * S + n] = __logf(p);
                }
            }
        }
    } else {
        const int rb = b - count;
        floatx4 acc[2];
        acc[0] = (floatx4)0.f; acc[1] = (floatx4)0.f;
#pragma unroll
        for (int kt = 0; kt < 4; kt++) {
            const int ko = kt * 32 + quad * 8;
            const bf16x8 ah = *reinterpret_cast<const bf16x8*>(&Rhi[(size_t)(rb * 16 + lr) * S + ko]);
            const bf16x8 al = *reinterpret_cast<const bf16x8*>(&Rlo[(size_t)(rb * 16 + lr) * S + ko]);
            const bf16x8 bh0 = *reinterpret_cast<const bf16x8*>(&Thi[(size_t)(w * 32 + lr) * S + ko]);
            const bf16x8 bh1 = *reinterpret_cast<const bf16x8*>(&Thi[(size_t)(w * 32 + 16 + lr) * S + ko]);
            const bf16x8 bl0 = *reinterpret_cast<const bf16x8*>(&Tlo[(size_t)(w * 32 + lr) * S + ko]);
            const bf16x8 bl1 = *reinterpret_cast<const bf16x8*>(&Tlo[(size_t)(w * 32 + 16 + lr) * S + ko]);
            acc[0] = __builtin_amdgcn_mfma_f32_16x16x32_bf16(ah, bh0, acc[0], 0, 0, 0);
            acc[0] = __builtin_amdgcn_mfma_f32_16x16x32_bf16(ah, bl0, acc[0], 0, 0, 0);
            acc[0] = __builtin_amdgcn_mfma_f32_16x16x32_bf16(al, bh0, acc[0], 0, 0, 0);
            acc[1] = __builtin_amdgcn_mfma_f32_16x16x32_bf16(ah, bh1, acc[1], 0, 0, 0);
            acc[1] = __builtin_amdgcn_mfma_f32_16x16x32_bf16(ah, bl1, acc[1], 0, 0, 0);
            acc[1] = __builtin_amdgcn_mfma_f32_16x16x32_bf16(al, bh1, acc[1], 0, 0, 0);
        }
#pragma unroll
        for (int nt = 0; nt < 2; nt++) {
#pragma unroll
            for (int reg = 0; reg < 4; reg++) {
                const int row = rb * 16 + quad * 4 + reg;
                const int col = w * 32 + nt * 16 + lr;
                const float p = acc[nt][reg];
                __bf16 hi, lo; split_bf16(p, hi, lo);
                Rnhi[(size_t)row * S + col] = hi; Rnlo[(size_t)row * S + col] = lo;
                Tnhi[(size_t)col * S + row] = hi; Tnlo[(size_t)col * S + row] = lo;
            }
        }
    }
}

// ---------------------------------------------------------------------------
// Observation GEMM v5: v4 tiling (1 t x 128 n per wave), but NT stores
// REMOVED. Theory: __builtin_nontemporal_store bypasses L2 write-combining,
// capping the 276 MB out1/out2 stream at ~2.2 TB/s effective (v4's burst-
// doubling was near-null -> row-activation locality exonerated; the nt path
// is the remaining difference vs the 6.3 TB/s fill stream). Plain stores
// drain through L2. Reads (pET 1 MB, Hb 4 MB) are small; L2 thrash risk
// bounded at ~+30 MB refetch.
//   out2[t,c,n] = log(O[c,n]);  out1[t,n] = log(sum_c pcw[t,c]*O[c,n])
// ---------------------------------------------------------------------------
__global__ __launch_bounds__(512, 4) void obs_mfma_kernel(
        const __bf16* __restrict__ Hb,    // [T,C,S] (hi plane)
        const __bf16* __restrict__ pET,   // [N,S]
        const float* __restrict__ pcw,    // [T,C]
        float* __restrict__ out1,
        float* __restrict__ out2) {
    constexpr int BPITCH = 264;  // bytes per LDS row (256 data + 8 pad)
    __shared__ __align__(16) unsigned char Bs[128 * BPITCH];  // 33 KB
    __shared__ float sw[8][C];

    const int tid = threadIdx.x;
    const int w = tid >> 6;
    const int lane = tid & 63;
    const int l31 = lane & 31;
    const int half = lane >> 5;
    const int nblk = blockIdx.x * 128;
    const int tbase = blockIdx.y * 8;
    const int t = tbase + w;           // wave owns one t, full 128-n width

    // Stage pET rows [nblk, nblk+128) into LDS (padded pitch, coalesced 16B).
#pragma unroll
    for (int p = 0; p < 4; p++) {
        const int idx = p * 512 + tid;     // 0..2047
        const int row = idx >> 4;          // 0..127
        const int c16 = idx & 15;          // 16B chunk within row
        const float4 v = *reinterpret_cast<const float4*>(
            pET + (size_t)(nblk + row) * S + c16 * 8);
        *reinterpret_cast<float4*>(Bs + row * BPITCH + c16 * 16) = v;
    }
    if (tid < 256) sw[tid >> 5][tid & 31] =
        pcw[(size_t)(tbase + (tid >> 5)) * C + (tid & 31)];
    __syncthreads();

    const __bf16* A = Hb + (size_t)t * C * S;

    floatx16 acc[4];   // [ntile], 128 n-cols for one t
#pragma unroll
    for (int nt = 0; nt < 4; nt++) acc[nt] = (floatx16)0.f;

#pragma unroll
    for (int ks = 0; ks < 8; ks++) {
        const int ko = ks * 16 + half * 8;
        const bf16x8 a  = *reinterpret_cast<const bf16x8*>(&A[(size_t)l31 * S + ko]);
        const bf16x8 b0 = *reinterpret_cast<const bf16x8*>(Bs + (l31) * BPITCH + ko * 2);
        const bf16x8 b1 = *reinterpret_cast<const bf16x8*>(Bs + (32 + l31) * BPITCH + ko * 2);
        const bf16x8 b2 = *reinterpret_cast<const bf16x8*>(Bs + (64 + l31) * BPITCH + ko * 2);
        const bf16x8 b3 = *reinterpret_cast<const bf16x8*>(Bs + (96 + l31) * BPITCH + ko * 2);
        acc[0] = __builtin_amdgcn_mfma_f32_32x32x16_bf16(a, b0, acc[0], 0, 0, 0);
        acc[1] = __builtin_amdgcn_mfma_f32_32x32x16_bf16(a, b1, acc[1], 0, 0, 0);
        acc[2] = __builtin_amdgcn_mfma_f32_32x32x16_bf16(a, b2, acc[2], 0, 0, 0);
        acc[3] = __builtin_amdgcn_mfma_f32_32x32x16_bf16(a, b3, acc[3], 0, 0, 0);
    }

    // Epilogue: per output row (t,c), write 4 consecutive 128 B chunks
    // (512 B contiguous burst) through L2; accumulate out1 partials.
    float p0 = 0.f, p1 = 0.f, p2 = 0.f, p3 = 0.f;
#pragma unroll
    for (int reg = 0; reg < 16; reg++) {
        const int c = (reg & 3) + 8 * (reg >> 2) + 4 * half;
        const float wv = sw[w][c];
        const float o0 = acc[0][reg];
        const float o1 = acc[1][reg];
        const float o2 = acc[2][reg];
        const float o3 = acc[3][reg];
        float* rowp = &out2[((size_t)t * C + c) * N + nblk + l31];
        rowp[0]  = __logf(o0);
        rowp[32] = __logf(o1);
        rowp[64] = __logf(o2);
        rowp[96] = __logf(o3);
        p0 = fmaf(wv, o0, p0);
        p1 = fmaf(wv, o1, p1);
        p2 = fmaf(wv, o2, p2);
        p3 = fmaf(wv, o3, p3);
    }
    p0 += __shfl_xor(p0, 32, 64);
    p1 += __shfl_xor(p1, 32, 64);
    p2 += __shfl_xor(p2, 32, 64);
    p3 += __shfl_xor(p3, 32, 64);
    if (half == 0) {
        float* o1p = &out1[(size_t)t * N + nblk + l31];
        o1p[0]  = __logf(p0);
        o1p[32] = __logf(p1);
        o1p[64] = __logf(p2);
        o1p[96] = __logf(p3);
    }
}

// ---------------------------------------------------------------------------
extern "C" void kernel_launch(void* const* d_in, const int* in_sizes, int n_in,
                              void* d_out, int out_size, void* d_ws, size_t ws_size,
                              hipStream_t stream) {
    const float* in_init  = (const float*)d_in[0];  // [C,S]
    const float* in_cw    = (const float*)d_in[1];  // [T,C]
    const float* in_emis  = (const float*)d_in[2];  // [S,N]
    const float* in_trans = (const float*)d_in[3];  // [S,S]

    float* out = (float*)d_out;

    // Workspace layout (~9.5 MB, 256B aligned)
    char* wsb = (char*)d_ws;
    float*  ws_pcw = (float*)(wsb);                                  // 64 KB [T,C]
    __bf16* ws_pET = (__bf16*)(wsb + (64u << 10));                   // 1 MB  [N,S]
    __bf16* ws_Hhi = (__bf16*)(wsb + (1088u << 10));                 // 4 MB  [T,C,S]
    __bf16* ws_Hlo = (__bf16*)(wsb + (5184u << 10));                 // 4 MB  [T,C,S]
    __bf16* Pslot[2][4];
    for (int sl = 0; sl < 2; sl++)
        for (int pl = 0; pl < 4; pl++)
            Pslot[sl][pl] = (__bf16*)(wsb + (9280u << 10) + (size_t)(sl * 4 + pl) * (32u << 10));

    // 1) All softmaxes in one launch.
    fused_softmax_kernel<<<352, 256, 0, stream>>>(
        in_emis, in_cw, in_trans, in_init,
        out + OFF3, out + OFF4, out + OFF5,
        ws_pET, ws_pcw,
        Pslot[0][0], Pslot[0][1], Pslot[0][2], Pslot[0][3],
        ws_Hhi, ws_Hlo);

    // 2) H-doubling rounds (hi/lo-pair MFMA), 9 separate launches (proven
    //    ~42 us total; cooperative-sync variant was 300 us).
    for (int r = 1; r <= 9; r++) {
        const int m = 1 << (r - 1);
        const int count = (m < T - m) ? m : (T - m);
        const int s = (r - 1) & 1, d = r & 1;
        const int extra = (r < 9) ? 8 : 0;
        h_round_kernel<<<count + extra, 256, 0, stream>>>(
            Pslot[s][0], Pslot[s][1], Pslot[s][2], Pslot[s][3],
            Pslot[d][0], Pslot[d][1], Pslot[d][2], Pslot[d][3],
            ws_Hhi, ws_Hlo, out + OFF3, m, count);
    }

    // 3) Observation GEMM v5: plain (through-L2) stores.
    obs_mfma_kernel<<<dim3(N / 128, T / 8), 512, 0, stream>>>(
        ws_Hhi, ws_pET, ws_pcw, out + OFF1, out + OFF2);
}